// Round 5
// baseline (697.606 us; speedup 1.0000x reference)
//
#include <hip/hip_runtime.h>

// CountSketch: out[b, i_hash[j]] += s_hash[j] * x[b, j]
//   x [16384, 8192] f32 (512 MB), hashes [8192], out [16384, 2048] f32 (128 MB)
//
// v15 = SCATTER formulation, persistent, single dispatch, no workspace.
// Rationale (v11..v14 post-mortems): the gather design needs a 64 KB LDS row
// dbuf -> 2 blocks/CU -> every row barrier-locks half the CU's waves; all
// attempts to restructure its schedule (v12,v13) or raise TLP inside one
// block (v14) regressed. Scatter removes row staging entirely:
//   - x read coalesced float4 -> REGISTERS (the 6.3 TB/s copy-bench regime),
//     register-double-buffered across rows (prefetch row r+1 while
//     scattering row r).
//   - sign multiply = xor on the f32 sign bit; ds_add_f32 into acc[2048].
//     Random hash -> ~2-way LDS conflicts (free per m136); compute ~600 cyc
//     per row vs ~15K cyc HBM wall at 4 blocks/CU.
//   - acc double-buffered (2 x 8 KB): store of row r-1 (+ rezero) overlaps
//     the scatter of row r; ONE lgkm-only barrier per row (s_barrier without
//     vmcnt drain -> global loads/stores stay in flight across it).
//   - hashes packed ONCE per block into 16 VGPRs (u16 = f | sign<<15);
//     no metadata refetch, no records, no caps, no leftovers -> handles any
//     hash distribution correctly (atomics), no prep kernels, no ws.
//   - 1024 blocks = 4 blocks/CU x 4 waves = 16 waves/CU in FOUR independent
//     barrier domains (v14 lesson: bigger barrier groups hurt; more
//     independent ones are how the copy bench saturates HBM).
//   - Ownership/stores stay lane-interleaved f = t + 256k (v13 lesson:
//     contiguous ownership = LDS bank conflicts).

typedef unsigned int u32;

constexpr int D_IN  = 8192;
constexpr int D_F   = 2048;
constexpr int BLOCK = 256;
constexpr int GRID  = 1024;     // 4 blocks/CU * 256 CU

#define ASM_LGKM0 asm volatile("s_waitcnt lgkmcnt(0)" ::: "memory")
#define SCHED0 __builtin_amdgcn_sched_barrier(0)
#define RAWBAR __builtin_amdgcn_s_barrier()
// end-of-row barrier: LDS ops visible; vmem loads/stores stay in flight
#define LBAR do { ASM_LGKM0; SCHED0; RAWBAR; SCHED0; } while (0)

__device__ __forceinline__ void scat(float* P, u32 h, float xv)
{
    u32 xb = __float_as_uint(xv) ^ ((h & 0x8000u) << 16);   // +-1 sign flip
    atomicAdd(&P[h & 0x7FFu], __uint_as_float(xb));          // ds_add_f32
}

__global__ __launch_bounds__(BLOCK, 4) void cs_main(
    const float* __restrict__ x, const float* __restrict__ s_hash,
    const int* __restrict__ i_hash, float* __restrict__ out, int batch)
{
    __shared__ float accA[D_F];     // 8 KB
    __shared__ float accB[D_F];     // 8 KB -> 16 KB/block
    const int t = threadIdx.x;
    const int G = gridDim.x;

    int row = blockIdx.x;
    if (row >= batch) return;       // uniform per block

    // ---- issue row-0 x loads first (hide behind prologue) ----
    float4 cur[8], nxt[8];
    {
        const float4* xr = (const float4*)(x + (size_t)row * D_IN);
        #pragma unroll
        for (int q = 0; q < 8; ++q) cur[q] = xr[q * BLOCK + t];
    }

    // ---- pack hashes once: thread t owns j = it*1024 + 4t .. +3 ----
    // ph[2*it]   = h(c0) | h(c1)<<16 ; ph[2*it+1] = h(c2) | h(c3)<<16
    // h(u16) = bucket(11b) | sign<<15
    u32 ph[16];
    #pragma unroll
    for (int it = 0; it < 8; ++it) {
        int4   iv = ((const int4*)  i_hash)[it * BLOCK + t];
        float4 sv = ((const float4*)s_hash)[it * BLOCK + t];
        u32 h0 = ((u32)iv.x & 0x7FFu) | ((__float_as_uint(sv.x) >> 31) << 15);
        u32 h1 = ((u32)iv.y & 0x7FFu) | ((__float_as_uint(sv.y) >> 31) << 15);
        u32 h2 = ((u32)iv.z & 0x7FFu) | ((__float_as_uint(sv.z) >> 31) << 15);
        u32 h3 = ((u32)iv.w & 0x7FFu) | ((__float_as_uint(sv.w) >> 31) << 15);
        ph[2 * it + 0] = h0 | (h1 << 16);
        ph[2 * it + 1] = h2 | (h3 << 16);
    }

    #pragma unroll
    for (int k = 0; k < D_F / BLOCK; ++k) {
        accA[t + BLOCK * k] = 0.0f;
        accB[t + BLOCK * k] = 0.0f;
    }
    __syncthreads();                // once; full drain acceptable here

    // ---- persistent row loop: one lgkm-barrier per row ----
    int prev = -1;
    bool useA = true;
    while (true) {
        const int next = row + G;

        // 1) prefetch next row into the other register set
        if (next < batch) {
            const float4* xn = (const float4*)(x + (size_t)next * D_IN);
            #pragma unroll
            for (int q = 0; q < 8; ++q) nxt[q] = xn[q * BLOCK + t];
        }

        float* P = useA ? accA : accB;      // scatter target (this row)
        float* Q = useA ? accB : accA;      // holds prev row's result

        // 2) store prev row from Q (+ rezero) — overlaps this row's scatter.
        //    Q's scatters finished before last iteration's LBAR.
        if (prev >= 0) {
            #pragma unroll
            for (int k = 0; k < D_F / BLOCK; ++k) {
                int f = t + BLOCK * k;
                out[(size_t)prev * D_F + f] = Q[f];
                Q[f] = 0.0f;
            }
        }

        // 3) scatter current row (branch-free, 32 ds_add_f32)
        #pragma unroll
        for (int it = 0; it < 8; ++it) {
            float4 xv = cur[it];
            u32 pa = ph[2 * it + 0], pb = ph[2 * it + 1];
            scat(P, pa & 0xFFFFu, xv.x);
            scat(P, pa >> 16,     xv.y);
            scat(P, pb & 0xFFFFu, xv.z);
            scat(P, pb >> 16,     xv.w);
        }

        // 4) end-of-row: scatters to P visible; rezero of Q visible;
        //    global loads/stores remain in flight
        LBAR;

        prev = row;
        row  = next;
        useA = !useA;
        if (row >= batch) break;
        #pragma unroll
        for (int q = 0; q < 8; ++q) cur[q] = nxt[q];
    }

    // ---- epilogue: last row sits in the buffer scattered last (old P) ----
    {
        float* Q = useA ? accB : accA;      // old P after the flip
        #pragma unroll
        for (int k = 0; k < D_F / BLOCK; ++k) {
            int f = t + BLOCK * k;
            out[(size_t)prev * D_F + f] = Q[f];
        }
    }
}

extern "C" void kernel_launch(void* const* d_in, const int* in_sizes, int n_in,
                              void* d_out, int out_size, void* d_ws, size_t ws_size,
                              hipStream_t stream)
{
    const float* x      = (const float*)d_in[0];
    const float* s_hash = (const float*)d_in[1];
    const int*   i_hash = (const int*)d_in[2];
    float*       out    = (float*)d_out;
    const int batch = in_sizes[0] / D_IN;
    if (batch <= 0) return;

    int grid = batch < GRID ? batch : GRID;
    cs_main<<<grid, BLOCK, 0, stream>>>(x, s_hash, i_hash, out, batch);
}

// Round 6
// 677.327 us; speedup vs baseline: 1.0299x; 1.0299x over previous
//
#include <hip/hip_runtime.h>

// CountSketch: out[b, i_hash[j]] += s_hash[j] * x[b, j]
//   x [16384, 8192] f32 (512 MB), hashes [8192], out [16384, 2048] f32 (128 MB)
//
// v16 = v15 (persistent scatter, single dispatch, no workspace) with the
// SPILL FIXED. v15's rocprof: VGPR_Count=64 but cur[8]+nxt[8]+ph[16] = 80+
// live regs -> compiler pushed the row double-buffer to scratch -> 697 us,
// VALUBusy 1.6%, HBM 0.6 TB/s. Fix: static half-row ping-pong in NAMED
// float4 scalars (a0..a3 / b0..b3 = 32 VGPRs), no array copies, no
// conditional loads (clamped prefetch row index) -> nothing can spill.
//
// Per row (steady state):
//   1) store prev row from Q (+rezero)           [global st, no waits]
//   2) issue B-half loads (row second half)      [4 dwordx4]
//   3) scatter A-half (16 ds_add_f32)            [waits on loads issued
//                                                 one iteration ago]
//   4) issue A-half loads for NEXT row           [4 dwordx4]
//   5) scatter B-half                            [covered by 3+4]
//   6) lgkm-only barrier (vmem stays in flight)
// acc double-buffered (2 x 8 KB LDS): store of row r-1 overlaps scatter of
// row r. 1024 blocks = 4 blocks/CU x 4 waves = 4 independent barrier
// domains per CU. Hashes packed once into 16 VGPRs (u16 = bucket|sign<<15).

typedef unsigned int u32;

constexpr int D_IN  = 8192;
constexpr int D_F   = 2048;
constexpr int BLOCK = 256;
constexpr int GRID  = 1024;     // 4 blocks/CU * 256 CU

#define ASM_LGKM0 asm volatile("s_waitcnt lgkmcnt(0)" ::: "memory")
#define SCHED0 __builtin_amdgcn_sched_barrier(0)
#define RAWBAR __builtin_amdgcn_s_barrier()
// end-of-row barrier: LDS ops visible; vmem loads/stores stay in flight
#define LBAR do { ASM_LGKM0; SCHED0; RAWBAR; SCHED0; } while (0)

__device__ __forceinline__ void scat(float* P, u32 h, float xv)
{
    u32 xb = __float_as_uint(xv) ^ ((h & 0x8000u) << 16);   // +-1 sign flip
    atomicAdd(&P[h & 0x7FFu], __uint_as_float(xb));          // ds_add_f32
}

__device__ __forceinline__ void scat4(float* P, u32 pa, u32 pb, float4 xv)
{
    scat(P, pa & 0xFFFFu, xv.x);
    scat(P, pa >> 16,     xv.y);
    scat(P, pb & 0xFFFFu, xv.z);
    scat(P, pb >> 16,     xv.w);
}

__global__ __launch_bounds__(BLOCK, 4) void cs_main(
    const float* __restrict__ x, const float* __restrict__ s_hash,
    const int* __restrict__ i_hash, float* __restrict__ out, int batch)
{
    __shared__ float acc[2][D_F];   // 16 KB
    const int t = threadIdx.x;
    const int G = gridDim.x;
    int row = blockIdx.x;

    // ---- pack hashes once: chunk c covers j = c*1024 + 4t .. +3 ----
    // ph[2c] = h(j0)|h(j1)<<16 ; ph[2c+1] = h(j2)|h(j3)<<16
    // h(u16) = bucket(11b) | sign<<15
    u32 ph[16];
    #pragma unroll
    for (int c = 0; c < 8; ++c) {
        int4   iv = ((const int4*)  i_hash)[c * BLOCK + t];
        float4 sv = ((const float4*)s_hash)[c * BLOCK + t];
        u32 h0 = ((u32)iv.x & 0x7FFu) | ((__float_as_uint(sv.x) >> 31) << 15);
        u32 h1 = ((u32)iv.y & 0x7FFu) | ((__float_as_uint(sv.y) >> 31) << 15);
        u32 h2 = ((u32)iv.z & 0x7FFu) | ((__float_as_uint(sv.z) >> 31) << 15);
        u32 h3 = ((u32)iv.w & 0x7FFu) | ((__float_as_uint(sv.w) >> 31) << 15);
        ph[2 * c + 0] = h0 | (h1 << 16);
        ph[2 * c + 1] = h2 | (h3 << 16);
    }

    #pragma unroll
    for (int k = 0; k < 2 * D_F / BLOCK; ++k)
        ((float*)acc)[t + BLOCK * k] = 0.0f;

    // ---- prologue: issue A-half loads for row 0 ----
    const float4* xv4 = (const float4*)x;
    size_t base = (size_t)row * (D_IN / 4);
    float4 a0 = xv4[base + 0 * BLOCK + t];
    float4 a1 = xv4[base + 1 * BLOCK + t];
    float4 a2 = xv4[base + 2 * BLOCK + t];
    float4 a3 = xv4[base + 3 * BLOCK + t];

    __syncthreads();    // acc zeroed (loads may drain here; prologue only)

    // ---- persistent row loop ----
    int prev = -1, flip = 0;
    while (row < batch) {
        const int next = row + G;
        const int nrow = next < batch ? next : row;   // clamped prefetch
        float* P = acc[flip];
        float* Q = acc[flip ^ 1];

        // 1) store prev row from Q (+rezero) — overlaps this row's scatter
        if (prev >= 0) {
            #pragma unroll
            for (int k = 0; k < D_F / BLOCK; ++k) {
                int f = t + BLOCK * k;
                out[(size_t)prev * D_F + f] = Q[f];
                Q[f] = 0.0f;
            }
        }

        // 2) issue B-half loads (this row, chunks 4..7)
        float4 b0 = xv4[base + 4 * BLOCK + t];
        float4 b1 = xv4[base + 5 * BLOCK + t];
        float4 b2 = xv4[base + 6 * BLOCK + t];
        float4 b3 = xv4[base + 7 * BLOCK + t];

        // 3) scatter A-half (loads issued one iteration ago)
        scat4(P, ph[0],  ph[1],  a0);
        scat4(P, ph[2],  ph[3],  a1);
        scat4(P, ph[4],  ph[5],  a2);
        scat4(P, ph[6],  ph[7],  a3);

        // 4) issue A-half loads for next row (chunks 0..3)
        const size_t nbase = (size_t)nrow * (D_IN / 4);
        a0 = xv4[nbase + 0 * BLOCK + t];
        a1 = xv4[nbase + 1 * BLOCK + t];
        a2 = xv4[nbase + 2 * BLOCK + t];
        a3 = xv4[nbase + 3 * BLOCK + t];

        // 5) scatter B-half (covered by steps 3+4)
        scat4(P, ph[8],  ph[9],  b0);
        scat4(P, ph[10], ph[11], b1);
        scat4(P, ph[12], ph[13], b2);
        scat4(P, ph[14], ph[15], b3);

        // 6) end-of-row: scatters to P and rezero of Q visible to all waves
        LBAR;

        prev = row;
        row  = next;
        base = nbase;
        flip ^= 1;
    }

    // ---- epilogue: last row sits in acc[flip^1] (old P) ----
    {
        const float* Q = acc[flip ^ 1];
        #pragma unroll
        for (int k = 0; k < D_F / BLOCK; ++k) {
            int f = t + BLOCK * k;
            out[(size_t)prev * D_F + f] = Q[f];
        }
    }
}

extern "C" void kernel_launch(void* const* d_in, const int* in_sizes, int n_in,
                              void* d_out, int out_size, void* d_ws, size_t ws_size,
                              hipStream_t stream)
{
    const float* x      = (const float*)d_in[0];
    const float* s_hash = (const float*)d_in[1];
    const int*   i_hash = (const int*)d_in[2];
    float*       out    = (float*)d_out;
    const int batch = in_sizes[0] / D_IN;
    if (batch <= 0) return;

    int grid = batch < GRID ? batch : GRID;
    cs_main<<<grid, BLOCK, 0, stream>>>(x, s_hash, i_hash, out, batch);
}